// Round 1
// baseline (2154.442 us; speedup 1.0000x reference)
//
#include <hip/hip_runtime.h>
#include <math.h>

constexpr int N = 20000, E = 160000, Bb = 1000;
constexpr int DIN = 7, HID = 64, HEADS = 4, CTXD = 3, EDIM = 5, NL = 4;
constexpr int HH = HEADS * HID; // 256

__device__ __forceinline__ float wredsum(float v) {
#pragma unroll
  for (int o = 32; o; o >>= 1) v += __shfl_xor(v, o, 64);
  return v;
}

// c = relu(context @ ctx_W + ctx_b) + form_tab[formation] + align_tab[alignment]
__global__ void k_ctx(const float* __restrict__ ctx, const float* __restrict__ ctx_W,
                      const float* __restrict__ ctx_b, const float* __restrict__ form_tab,
                      const float* __restrict__ align_tab, const int* __restrict__ form,
                      const int* __restrict__ alig, float* __restrict__ c_out) {
  int t = blockIdx.x * blockDim.x + threadIdx.x;
  if (t >= Bb * HID) return;
  int b = t >> 6, j = t & 63;
  float a = ctx_b[j];
#pragma unroll
  for (int k = 0; k < CTXD; ++k) a += ctx[b * CTXD + k] * ctx_W[k * HID + j];
  a = fmaxf(a, 0.f);
  a += form_tab[form[b] * HID + j] + align_tab[alig[b] * HID + j];
  c_out[t] = a;
}

__global__ void k_node_init(const float* __restrict__ x, const float* __restrict__ emb_W,
                            const float* __restrict__ emb_b, const int* __restrict__ role,
                            const float* __restrict__ role_tab, const int* __restrict__ side,
                            const float* __restrict__ side_tab, const float* __restrict__ frame_t,
                            const float* __restrict__ temp_tab, const int* __restrict__ batch,
                            const float* __restrict__ c_ctx, float* __restrict__ h) {
  int t = blockIdx.x * blockDim.x + threadIdx.x;
  if (t >= N * HID) return;
  int n = t >> 6, j = t & 63;
  float a = emb_b[j];
#pragma unroll
  for (int k = 0; k < DIN; ++k) a += x[n * DIN + k] * emb_W[k * HID + j];
  a = fmaxf(a, 0.f);
  a += role_tab[role[n] * HID + j];
  if (j < 32) a += side_tab[side[n] * 32 + j];
  int ti = (int)(frame_t[0] * 99.f);
  ti = ti < 0 ? 0 : (ti > 99 ? 99 : ti);
  a += temp_tab[ti * HID + j];
  a += c_ctx[batch[n] * HID + j];
  h[t] = a;
}

__global__ void k_count(const int* __restrict__ ei, int* __restrict__ deg_dst,
                        int* __restrict__ deg_src) {
  int e = blockIdx.x * blockDim.x + threadIdx.x;
  if (e >= E) return;
  atomicAdd(&deg_src[ei[e]], 1);
  atomicAdd(&deg_dst[ei[E + e]], 1);
}

// single-block exclusive scan: row[i] = sum(deg[0..i)), cur = copy of row
__global__ void k_scan(const int* __restrict__ deg, int* __restrict__ row,
                       int* __restrict__ cur, int n) {
  __shared__ int sd[1024];
  __shared__ int carry;
  int t = threadIdx.x;
  if (t == 0) carry = 0;
  __syncthreads();
  for (int base = 0; base < n; base += 1024) {
    int v = (base + t < n) ? deg[base + t] : 0;
    sd[t] = v;
    __syncthreads();
    for (int off = 1; off < 1024; off <<= 1) {
      int self = sd[t];
      int xo = (t >= off) ? sd[t - off] : 0;
      __syncthreads();
      sd[t] = self + xo;
      __syncthreads();
    }
    if (base + t < n) {
      int r = carry + sd[t] - v;
      row[base + t] = r;
      cur[base + t] = r;
    }
    __syncthreads();
    if (t == 0) carry += sd[1023];
    __syncthreads();
  }
}

__global__ void k_scatter(const int* __restrict__ ei, int* __restrict__ cur_dst,
                          int* __restrict__ cur_src, int* __restrict__ eid_dst,
                          int* __restrict__ eid_src) {
  int e = blockIdx.x * blockDim.x + threadIdx.x;
  if (e >= E) return;
  int s = ei[e], d = ei[E + e];
  eid_src[atomicAdd(&cur_src[s], 1)] = e;
  eid_dst[atomicAdd(&cur_dst[d], 1)] = e;
}

// loop_attr[n] = mean of edge_attr over incoming edges (0 if none)
__global__ void k_loop_attr(const int* __restrict__ row_dst, const int* __restrict__ deg_dst,
                            const int* __restrict__ eid_dst, const float* __restrict__ ea,
                            float* __restrict__ la) {
  int n = blockIdx.x * blockDim.x + threadIdx.x;
  if (n >= N) return;
  int beg = row_dst[n], cnt = deg_dst[n];
  float s[EDIM] = {0.f, 0.f, 0.f, 0.f, 0.f};
  for (int j = 0; j < cnt; ++j) {
    int e = eid_dst[beg + j];
#pragma unroll
    for (int k = 0; k < EDIM; ++k) s[k] += ea[(size_t)e * EDIM + k];
  }
  float inv = 1.f / fmaxf((float)cnt, 1.f);
#pragma unroll
  for (int k = 0; k < EDIM; ++k) la[n * EDIM + k] = s[k] * inv;
}

// xl = h@Wl + bl, xr = h@Wr + br  (weights column-stationary in VGPRs)
__global__ __launch_bounds__(256) void k_xlxr(const float* __restrict__ h,
                                              const float* __restrict__ Wl,
                                              const float* __restrict__ bl,
                                              const float* __restrict__ Wr,
                                              const float* __restrict__ br,
                                              float* __restrict__ xl, float* __restrict__ xr) {
  constexpr int NB = 16;
  __shared__ float hs[NB][HID];
  int n0 = blockIdx.x * NB;
  for (int idx = threadIdx.x; idx < NB * HID; idx += 256) {
    int r = idx >> 6, c = idx & 63;
    int n = n0 + r;
    hs[r][c] = (n < N) ? h[n * HID + c] : 0.f;
  }
  __syncthreads();
  int t = threadIdx.x;
  float wl[HID], wr[HID];
#pragma unroll
  for (int k = 0; k < HID; ++k) {
    wl[k] = Wl[k * HH + t];
    wr[k] = Wr[k * HH + t];
  }
  float blv = bl[t], brv = br[t];
  for (int r = 0; r < NB; ++r) {
    int n = n0 + r;
    if (n >= N) break;
    float al = blv, ar = brv;
#pragma unroll
    for (int k = 0; k < HID; ++k) {
      float hv = hs[r][k];
      al += hv * wl[k];
      ar += hv * wr[k];
    }
    xl[(size_t)n * HH + t] = al;
    xr[(size_t)n * HH + t] = ar;
  }
}

// per-node fused GATv2: online segment-softmax + weighted agg + head-mean + relu + LN(residual)
__global__ __launch_bounds__(256) void k_gat(
    const float* __restrict__ xl, const float* __restrict__ xr, const int* __restrict__ ei,
    const float* __restrict__ ea, const float* __restrict__ la, const int* __restrict__ row_dst,
    const int* __restrict__ deg_dst, const int* __restrict__ eid_dst,
    const float* __restrict__ We, const float* __restrict__ att, const float* __restrict__ biasL,
    const float* __restrict__ lng, const float* __restrict__ lnb, float* __restrict__ h) {
  int n = blockIdx.x;
  int w = threadIdx.x >> 6, lane = threadIdx.x & 63;
  int col = w * HID + lane;
  float xr_d = xr[(size_t)n * HH + col];
  float attw = att[col];
  float we[EDIM];
#pragma unroll
  for (int k = 0; k < EDIM; ++k) we[k] = We[k * HH + col];
  float m = -INFINITY, s = 0.f, acc = 0.f;
  int beg = row_dst[n], cnt = deg_dst[n];
  for (int idx = 0; idx <= cnt; ++idx) {
    int srcn;
    const float* eap;
    if (idx == 0) {
      srcn = n;
      eap = la + (size_t)n * EDIM;
    } else {
      int e = eid_dst[beg + idx - 1];
      srcn = ei[e];
      eap = ea + (size_t)e * EDIM;
    }
    float ep = 0.f;
#pragma unroll
    for (int k = 0; k < EDIM; ++k) ep += eap[k] * we[k];
    float xls = xl[(size_t)srcn * HH + col];
    float v = xls + xr_d + ep;
    v = v > 0.f ? v : 0.2f * v;
    float lg = wredsum(v * attw);
    float nm = fmaxf(m, lg);
    float sc = expf(m - nm);  // first iter: exp(-inf)=0
    float p = expf(lg - nm);
    s = s * sc + p;
    acc = acc * sc + p * xls;
    m = nm;
  }
  float outv = acc / (s + 1e-16f);
  __shared__ float heads[HEADS][HID];
  heads[w][lane] = outv;
  __syncthreads();
  if (w == 0) {
    float hv = (heads[0][lane] + heads[1][lane] + heads[2][lane] + heads[3][lane]) * 0.25f +
               biasL[lane];
    hv = fmaxf(hv, 0.f);
    float v = hv + h[n * HID + lane];
    float mu = wredsum(v) * (1.f / 64.f);
    float d = v - mu;
    float var = wredsum(d * d) * (1.f / 64.f);
    h[n * HID + lane] = d * rsqrtf(var + 1e-5f) * lng[lane] + lnb[lane];
  }
}

// social pooling edge MLP: one wave per edge, weights (exactly 64KB) in LDS
__global__ __launch_bounds__(256) void k_sp(const float* __restrict__ h,
                                            const int* __restrict__ ei,
                                            const float* __restrict__ W1,
                                            const float* __restrict__ b1,
                                            const float* __restrict__ W2,
                                            const float* __restrict__ b2,
                                            const float* __restrict__ Wg,
                                            const float* __restrict__ bg,
                                            float* __restrict__ pooled) {
  __shared__ float Ws[128 * 64 + 64 * 64 + 64 * 64];  // 16384 f32 = 64 KiB
  for (int i = threadIdx.x; i < 128 * 64; i += 256) Ws[i] = W1[i];
  for (int i = threadIdx.x; i < 64 * 64; i += 256) {
    Ws[8192 + i] = W2[i];
    Ws[12288 + i] = Wg[i];
  }
  __syncthreads();
  int w = threadIdx.x >> 6, lane = threadIdx.x & 63;
  float b1r = b1[lane], b2r = b2[lane], bgr = bg[lane];
  for (int e = blockIdx.x * 4 + w; e < E; e += gridDim.x * 4) {
    int s = ei[e], d = ei[E + e];
    float hsv = h[s * HID + lane], hdv = h[d * HID + lane];
    float pre = b1r;
#pragma unroll
    for (int k = 0; k < 64; ++k) pre += __shfl(hsv, k, 64) * Ws[k * 64 + lane];
#pragma unroll
    for (int k = 0; k < 64; ++k) pre += __shfl(hdv, k, 64) * Ws[(64 + k) * 64 + lane];
    pre = fmaxf(pre, 0.f);
    float inter = b2r;
#pragma unroll
    for (int k = 0; k < 64; ++k) inter += __shfl(pre, k, 64) * Ws[8192 + k * 64 + lane];
    float gp = bgr;
#pragma unroll
    for (int k = 0; k < 64; ++k) gp += __shfl(inter, k, 64) * Ws[12288 + k * 64 + lane];
    float gated = inter / (1.f + expf(-gp));
    atomicAdd(&pooled[s * HID + lane], gated);
  }
}

__global__ void k_final(const float* __restrict__ h, const float* __restrict__ pooled,
                        const int* __restrict__ deg_src, const float* __restrict__ g,
                        const float* __restrict__ b, float* __restrict__ out) {
  int n = blockIdx.x * 4 + (threadIdx.x >> 6);
  int lane = threadIdx.x & 63;
  if (n >= N) return;
  float cntv = fmaxf((float)deg_src[n], 1.f);
  float v = h[n * HID + lane] + pooled[n * HID + lane] / cntv;
  float mu = wredsum(v) * (1.f / 64.f);
  float d = v - mu;
  float var = wredsum(d * d) * (1.f / 64.f);
  out[n * HID + lane] = d * rsqrtf(var + 1e-5f) * g[lane] + b[lane];
}

extern "C" void kernel_launch(void* const* d_in, const int* in_sizes, int n_in, void* d_out,
                              int out_size, void* d_ws, size_t ws_size, hipStream_t stream) {
  const float* x = (const float*)d_in[0];
  const int* ei = (const int*)d_in[1];
  const float* eattr = (const float*)d_in[2];
  const float* ctx = (const float*)d_in[3];
  const int* batch = (const int*)d_in[4];
  const int* role = (const int*)d_in[5];
  const int* side = (const int*)d_in[6];
  const int* form = (const int*)d_in[7];
  const int* alig = (const int*)d_in[8];
  const float* frame_t = (const float*)d_in[9];
  const float* emb_W = (const float*)d_in[10];
  const float* emb_b = (const float*)d_in[11];
  const float* role_tab = (const float*)d_in[12];
  const float* side_tab = (const float*)d_in[13];
  const float* ctx_W = (const float*)d_in[14];
  const float* ctx_b = (const float*)d_in[15];
  const float* form_tab = (const float*)d_in[16];
  const float* align_tab = (const float*)d_in[17];
  const float* temp_tab = (const float*)d_in[18];
  const float* gat_Wl = (const float*)d_in[19];
  const float* gat_bl = (const float*)d_in[20];
  const float* gat_Wr = (const float*)d_in[21];
  const float* gat_br = (const float*)d_in[22];
  const float* gat_We = (const float*)d_in[23];
  const float* gat_att = (const float*)d_in[24];
  const float* gat_bias = (const float*)d_in[25];
  const float* ln_g = (const float*)d_in[26];
  const float* ln_b = (const float*)d_in[27];
  const float* sp_W1 = (const float*)d_in[28];
  const float* sp_b1 = (const float*)d_in[29];
  const float* sp_W2 = (const float*)d_in[30];
  const float* sp_b2 = (const float*)d_in[31];
  const float* sp_Wg = (const float*)d_in[32];
  const float* sp_bg = (const float*)d_in[33];
  const float* fn_g = (const float*)d_in[34];
  const float* fn_b = (const float*)d_in[35];
  float* out = (float*)d_out;

  char* wp = (char*)d_ws;
  auto alloc = [&](size_t bytes) {
    void* p = (void*)wp;
    wp += (bytes + 255) & ~(size_t)255;
    return p;
  };
  float* c_ctx = (float*)alloc((size_t)Bb * HID * 4);
  float* h = (float*)alloc((size_t)N * HID * 4);
  float* xl = (float*)alloc((size_t)N * HH * 4);
  float* xr = (float*)alloc((size_t)N * HH * 4);
  float* la = (float*)alloc((size_t)N * EDIM * 4);
  float* pooled = (float*)alloc((size_t)N * HID * 4);
  int* deg_dst = (int*)alloc((size_t)N * 4);
  int* deg_src = (int*)alloc((size_t)N * 4);
  int* row_dst = (int*)alloc((size_t)N * 4);
  int* row_src = (int*)alloc((size_t)N * 4);
  int* cur_dst = (int*)alloc((size_t)N * 4);
  int* cur_src = (int*)alloc((size_t)N * 4);
  int* eid_dst = (int*)alloc((size_t)E * 4);
  int* eid_src = (int*)alloc((size_t)E * 4);

  hipMemsetAsync(deg_dst, 0, (size_t)N * 4, stream);
  hipMemsetAsync(deg_src, 0, (size_t)N * 4, stream);
  hipMemsetAsync(pooled, 0, (size_t)N * HID * 4, stream);

  k_ctx<<<(Bb * HID + 255) / 256, 256, 0, stream>>>(ctx, ctx_W, ctx_b, form_tab, align_tab, form,
                                                    alig, c_ctx);
  k_node_init<<<(N * HID + 255) / 256, 256, 0, stream>>>(x, emb_W, emb_b, role, role_tab, side,
                                                         side_tab, frame_t, temp_tab, batch, c_ctx,
                                                         h);
  k_count<<<(E + 255) / 256, 256, 0, stream>>>(ei, deg_dst, deg_src);
  k_scan<<<1, 1024, 0, stream>>>(deg_dst, row_dst, cur_dst, N);
  k_scan<<<1, 1024, 0, stream>>>(deg_src, row_src, cur_src, N);
  k_scatter<<<(E + 255) / 256, 256, 0, stream>>>(ei, cur_dst, cur_src, eid_dst, eid_src);
  k_loop_attr<<<(N + 255) / 256, 256, 0, stream>>>(row_dst, deg_dst, eid_dst, eattr, la);

  for (int i = 0; i < NL; ++i) {
    k_xlxr<<<(N + 15) / 16, 256, 0, stream>>>(h, gat_Wl + (size_t)i * HID * HH, gat_bl + i * HH,
                                              gat_Wr + (size_t)i * HID * HH, gat_br + i * HH, xl,
                                              xr);
    k_gat<<<N, 256, 0, stream>>>(xl, xr, ei, eattr, la, row_dst, deg_dst, eid_dst,
                                 gat_We + (size_t)i * EDIM * HH, gat_att + i * HH,
                                 gat_bias + i * HID, ln_g + i * HID, ln_b + i * HID, h);
  }

  k_sp<<<1024, 256, 0, stream>>>(h, ei, sp_W1, sp_b1, sp_W2, sp_b2, sp_Wg, sp_bg, pooled);
  k_final<<<(N + 3) / 4, 256, 0, stream>>>(h, pooled, deg_src, fn_g, fn_b, out);
}

// Round 2
// 928.416 us; speedup vs baseline: 2.3206x; 2.3206x over previous
//
#include <hip/hip_runtime.h>
#include <math.h>

constexpr int N = 20000, E = 160000, Bb = 1000;
constexpr int DIN = 7, HID = 64, HEADS = 4, CTXD = 3, EDIM = 5, NL = 4;
constexpr int HH = HEADS * HID; // 256

__device__ __forceinline__ float wredsum(float v) {
#pragma unroll
  for (int o = 32; o; o >>= 1) v += __shfl_xor(v, o, 64);
  return v;
}

__global__ void k_ctx(const float* __restrict__ ctx, const float* __restrict__ ctx_W,
                      const float* __restrict__ ctx_b, const float* __restrict__ form_tab,
                      const float* __restrict__ align_tab, const int* __restrict__ form,
                      const int* __restrict__ alig, float* __restrict__ c_out) {
  int t = blockIdx.x * blockDim.x + threadIdx.x;
  if (t >= Bb * HID) return;
  int b = t >> 6, j = t & 63;
  float a = ctx_b[j];
#pragma unroll
  for (int k = 0; k < CTXD; ++k) a += ctx[b * CTXD + k] * ctx_W[k * HID + j];
  a = fmaxf(a, 0.f);
  a += form_tab[form[b] * HID + j] + align_tab[alig[b] * HID + j];
  c_out[t] = a;
}

__global__ void k_node_init(const float* __restrict__ x, const float* __restrict__ emb_W,
                            const float* __restrict__ emb_b, const int* __restrict__ role,
                            const float* __restrict__ role_tab, const int* __restrict__ side,
                            const float* __restrict__ side_tab, const float* __restrict__ frame_t,
                            const float* __restrict__ temp_tab, const int* __restrict__ batch,
                            const float* __restrict__ c_ctx, float* __restrict__ h) {
  int t = blockIdx.x * blockDim.x + threadIdx.x;
  if (t >= N * HID) return;
  int n = t >> 6, j = t & 63;
  float a = emb_b[j];
#pragma unroll
  for (int k = 0; k < DIN; ++k) a += x[n * DIN + k] * emb_W[k * HID + j];
  a = fmaxf(a, 0.f);
  a += role_tab[role[n] * HID + j];
  if (j < 32) a += side_tab[side[n] * 32 + j];
  int ti = (int)(frame_t[0] * 99.f);
  ti = ti < 0 ? 0 : (ti > 99 ? 99 : ti);
  a += temp_tab[ti * HID + j];
  a += c_ctx[batch[n] * HID + j];
  h[t] = a;
}

__global__ void k_count(const int* __restrict__ ei, int* __restrict__ deg_dst,
                        int* __restrict__ deg_src) {
  int e = blockIdx.x * blockDim.x + threadIdx.x;
  if (e >= E) return;
  atomicAdd(&deg_src[ei[e]], 1);
  atomicAdd(&deg_dst[ei[E + e]], 1);
}

__global__ void k_scan(const int* __restrict__ deg, int* __restrict__ row,
                       int* __restrict__ cur, int n) {
  __shared__ int sd[1024];
  __shared__ int carry;
  int t = threadIdx.x;
  if (t == 0) carry = 0;
  __syncthreads();
  for (int base = 0; base < n; base += 1024) {
    int v = (base + t < n) ? deg[base + t] : 0;
    sd[t] = v;
    __syncthreads();
    for (int off = 1; off < 1024; off <<= 1) {
      int self = sd[t];
      int xo = (t >= off) ? sd[t - off] : 0;
      __syncthreads();
      sd[t] = self + xo;
      __syncthreads();
    }
    if (base + t < n) {
      int r = carry + sd[t] - v;
      row[base + t] = r;
      cur[base + t] = r;
    }
    __syncthreads();
    if (t == 0) carry += sd[1023];
    __syncthreads();
  }
}

// also emits esrc_dst: src node id, stored in dst-sorted position (kills one
// dependent load level in k_gat)
__global__ void k_scatter(const int* __restrict__ ei, int* __restrict__ cur_dst,
                          int* __restrict__ cur_src, int* __restrict__ eid_dst,
                          int* __restrict__ eid_src, int* __restrict__ esrc_dst) {
  int e = blockIdx.x * blockDim.x + threadIdx.x;
  if (e >= E) return;
  int s = ei[e], d = ei[E + e];
  eid_src[atomicAdd(&cur_src[s], 1)] = e;
  int pd = atomicAdd(&cur_dst[d], 1);
  eid_dst[pd] = e;
  esrc_dst[pd] = s;
}

__global__ void k_loop_attr(const int* __restrict__ row_dst, const int* __restrict__ deg_dst,
                            const int* __restrict__ eid_dst, const float* __restrict__ ea,
                            float* __restrict__ la) {
  int n = blockIdx.x * blockDim.x + threadIdx.x;
  if (n >= N) return;
  int beg = row_dst[n], cnt = deg_dst[n];
  float s[EDIM] = {0.f, 0.f, 0.f, 0.f, 0.f};
  for (int j = 0; j < cnt; ++j) {
    int e = eid_dst[beg + j];
#pragma unroll
    for (int k = 0; k < EDIM; ++k) s[k] += ea[(size_t)e * EDIM + k];
  }
  float inv = 1.f / fmaxf((float)cnt, 1.f);
#pragma unroll
  for (int k = 0; k < EDIM; ++k) la[n * EDIM + k] = s[k] * inv;
}

__global__ __launch_bounds__(256) void k_xlxr(const float* __restrict__ h,
                                              const float* __restrict__ Wl,
                                              const float* __restrict__ bl,
                                              const float* __restrict__ Wr,
                                              const float* __restrict__ br,
                                              float* __restrict__ xl, float* __restrict__ xr) {
  constexpr int NB = 16;
  __shared__ float hs[NB][HID];
  int n0 = blockIdx.x * NB;
  for (int idx = threadIdx.x; idx < NB * HID; idx += 256) {
    int r = idx >> 6, c = idx & 63;
    int n = n0 + r;
    hs[r][c] = (n < N) ? h[n * HID + c] : 0.f;
  }
  __syncthreads();
  int t = threadIdx.x;
  float wl[HID], wr[HID];
#pragma unroll
  for (int k = 0; k < HID; ++k) {
    wl[k] = Wl[k * HH + t];
    wr[k] = Wr[k * HH + t];
  }
  float blv = bl[t], brv = br[t];
  for (int r = 0; r < NB; ++r) {
    int n = n0 + r;
    if (n >= N) break;
    float al = blv, ar = brv;
#pragma unroll
    for (int k = 0; k < HID; ++k) {
      float hv = hs[r][k];
      al += hv * wl[k];
      ar += hv * wr[k];
    }
    xl[(size_t)n * HH + t] = al;
    xr[(size_t)n * HH + t] = ar;
  }
}

__global__ __launch_bounds__(256) void k_gat(
    const float* __restrict__ xl, const float* __restrict__ xr,
    const float* __restrict__ ea, const float* __restrict__ la, const int* __restrict__ row_dst,
    const int* __restrict__ deg_dst, const int* __restrict__ eid_dst,
    const int* __restrict__ esrc_dst,
    const float* __restrict__ We, const float* __restrict__ att, const float* __restrict__ biasL,
    const float* __restrict__ lng, const float* __restrict__ lnb, float* __restrict__ h) {
  int n = blockIdx.x;
  int w = threadIdx.x >> 6, lane = threadIdx.x & 63;
  int col = w * HID + lane;
  float xr_d = xr[(size_t)n * HH + col];
  float attw = att[col];
  float we[EDIM];
#pragma unroll
  for (int k = 0; k < EDIM; ++k) we[k] = We[k * HH + col];
  float m = -INFINITY, s = 0.f, acc = 0.f;
  int beg = row_dst[n], cnt = deg_dst[n];
  for (int idx = 0; idx <= cnt; ++idx) {
    int srcn;
    const float* eap;
    if (idx == 0) {
      srcn = n;
      eap = la + (size_t)n * EDIM;
    } else {
      int pos = beg + idx - 1;
      srcn = esrc_dst[pos];
      int e = eid_dst[pos];
      eap = ea + (size_t)e * EDIM;
    }
    float ep = 0.f;
#pragma unroll
    for (int k = 0; k < EDIM; ++k) ep += eap[k] * we[k];
    float xls = xl[(size_t)srcn * HH + col];
    float v = xls + xr_d + ep;
    v = v > 0.f ? v : 0.2f * v;
    float lg = wredsum(v * attw);
    float nm = fmaxf(m, lg);
    float sc = expf(m - nm);
    float p = expf(lg - nm);
    s = s * sc + p;
    acc = acc * sc + p * xls;
    m = nm;
  }
  float outv = acc / (s + 1e-16f);
  __shared__ float heads[HEADS][HID];
  heads[w][lane] = outv;
  __syncthreads();
  if (w == 0) {
    float hv = (heads[0][lane] + heads[1][lane] + heads[2][lane] + heads[3][lane]) * 0.25f +
               biasL[lane];
    hv = fmaxf(hv, 0.f);
    float v = hv + h[n * HID + lane];
    float mu = wredsum(v) * (1.f / 64.f);
    float d = v - mu;
    float var = wredsum(d * d) * (1.f / 64.f);
    h[n * HID + lane] = d * rsqrtf(var + 1e-5f) * lng[lane] + lnb[lane];
  }
}

// u = h @ W1[:64] + b1 ; v = h @ W1[64:]   (per-node halves of the pair MLP)
__global__ __launch_bounds__(256) void k_uv(const float* __restrict__ h,
                                            const float* __restrict__ W1,
                                            const float* __restrict__ b1,
                                            float* __restrict__ u, float* __restrict__ v) {
  constexpr int NB = 16;
  __shared__ float hs[NB][HID];
  int n0 = blockIdx.x * NB;
  for (int idx = threadIdx.x; idx < NB * HID; idx += 256) {
    int r = idx >> 6, c = idx & 63;
    int n = n0 + r;
    hs[r][c] = (n < N) ? h[n * HID + c] : 0.f;
  }
  __syncthreads();
  int j = threadIdx.x & 63, q = threadIdx.x >> 6;
  float wa[HID], wb[HID];
#pragma unroll
  for (int k = 0; k < HID; ++k) {
    wa[k] = W1[k * HID + j];
    wb[k] = W1[(HID + k) * HID + j];
  }
  float b1v = b1[j];
  for (int r = q; r < NB; r += 4) {
    int n = n0 + r;
    if (n >= N) continue;
    float au = b1v, av = 0.f;
#pragma unroll
    for (int k = 0; k < HID; ++k) {
      float hv = hs[r][k];
      au += hv * wa[k];
      av += hv * wb[k];
    }
    u[(size_t)n * HID + j] = au;
    v[(size_t)n * HID + j] = av;
  }
}

// thread-owns-edge: pre/inter in VGPRs, weights via uniform (scalar) loads.
// Edges processed in src-sorted order; gated written positionally so the
// pooling pass is a contiguous segmented sum (no atomics).
__global__ __launch_bounds__(256) void k_edge(const float* __restrict__ u,
                                              const float* __restrict__ v,
                                              const int* __restrict__ ei,
                                              const int* __restrict__ eid_src,
                                              const float* __restrict__ W2,
                                              const float* __restrict__ b2,
                                              const float* __restrict__ Wg,
                                              const float* __restrict__ bg,
                                              float* __restrict__ gated) {
  int p = blockIdx.x * 256 + threadIdx.x;
  if (p >= E) return;
  int e = eid_src[p];
  int s = ei[e], d = ei[E + e];
  const float* ur = u + (size_t)s * HID;
  const float* vr = v + (size_t)d * HID;
  float pre[HID];
#pragma unroll
  for (int q = 0; q < 16; ++q) {
    float4 a = *(const float4*)(ur + 4 * q);
    float4 b = *(const float4*)(vr + 4 * q);
    pre[4 * q + 0] = fmaxf(a.x + b.x, 0.f);
    pre[4 * q + 1] = fmaxf(a.y + b.y, 0.f);
    pre[4 * q + 2] = fmaxf(a.z + b.z, 0.f);
    pre[4 * q + 3] = fmaxf(a.w + b.w, 0.f);
  }
  float it[HID];
#pragma unroll
  for (int jb = 0; jb < 8; ++jb) {
    float a0 = b2[jb * 8 + 0], a1 = b2[jb * 8 + 1], a2 = b2[jb * 8 + 2], a3 = b2[jb * 8 + 3];
    float a4 = b2[jb * 8 + 4], a5 = b2[jb * 8 + 5], a6 = b2[jb * 8 + 6], a7 = b2[jb * 8 + 7];
#pragma unroll
    for (int k = 0; k < HID; ++k) {
      const float* wr = W2 + k * HID + jb * 8;
      float pk = pre[k];
      a0 += pk * wr[0]; a1 += pk * wr[1]; a2 += pk * wr[2]; a3 += pk * wr[3];
      a4 += pk * wr[4]; a5 += pk * wr[5]; a6 += pk * wr[6]; a7 += pk * wr[7];
    }
    it[jb * 8 + 0] = a0; it[jb * 8 + 1] = a1; it[jb * 8 + 2] = a2; it[jb * 8 + 3] = a3;
    it[jb * 8 + 4] = a4; it[jb * 8 + 5] = a5; it[jb * 8 + 6] = a6; it[jb * 8 + 7] = a7;
  }
  float* gout = gated + (size_t)p * HID;
#pragma unroll
  for (int jb = 0; jb < 8; ++jb) {
    float g0 = bg[jb * 8 + 0], g1 = bg[jb * 8 + 1], g2 = bg[jb * 8 + 2], g3 = bg[jb * 8 + 3];
    float g4 = bg[jb * 8 + 4], g5 = bg[jb * 8 + 5], g6 = bg[jb * 8 + 6], g7 = bg[jb * 8 + 7];
#pragma unroll
    for (int k = 0; k < HID; ++k) {
      const float* wr = Wg + k * HID + jb * 8;
      float ik = it[k];
      g0 += ik * wr[0]; g1 += ik * wr[1]; g2 += ik * wr[2]; g3 += ik * wr[3];
      g4 += ik * wr[4]; g5 += ik * wr[5]; g6 += ik * wr[6]; g7 += ik * wr[7];
    }
    float4 o0, o1;
    o0.x = it[jb * 8 + 0] / (1.f + expf(-g0));
    o0.y = it[jb * 8 + 1] / (1.f + expf(-g1));
    o0.z = it[jb * 8 + 2] / (1.f + expf(-g2));
    o0.w = it[jb * 8 + 3] / (1.f + expf(-g3));
    o1.x = it[jb * 8 + 4] / (1.f + expf(-g4));
    o1.y = it[jb * 8 + 5] / (1.f + expf(-g5));
    o1.z = it[jb * 8 + 6] / (1.f + expf(-g6));
    o1.w = it[jb * 8 + 7] / (1.f + expf(-g7));
    *(float4*)(gout + jb * 8) = o0;
    *(float4*)(gout + jb * 8 + 4) = o1;
  }
}

// pooled mean (contiguous segmented sum over src-sorted gated) + final LN
__global__ void k_pool(const float* __restrict__ h, const float* __restrict__ gated,
                       const int* __restrict__ row_src, const int* __restrict__ deg_src,
                       const float* __restrict__ g, const float* __restrict__ b,
                       float* __restrict__ out) {
  int n = blockIdx.x * 4 + (threadIdx.x >> 6);
  int lane = threadIdx.x & 63;
  if (n >= N) return;
  int beg = row_src[n], cnt = deg_src[n];
  float acc = 0.f;
  for (int i = 0; i < cnt; ++i) acc += gated[(size_t)(beg + i) * HID + lane];
  float v = h[n * HID + lane] + acc / fmaxf((float)cnt, 1.f);
  float mu = wredsum(v) * (1.f / 64.f);
  float d = v - mu;
  float var = wredsum(d * d) * (1.f / 64.f);
  out[n * HID + lane] = d * rsqrtf(var + 1e-5f) * g[lane] + b[lane];
}

extern "C" void kernel_launch(void* const* d_in, const int* in_sizes, int n_in, void* d_out,
                              int out_size, void* d_ws, size_t ws_size, hipStream_t stream) {
  const float* x = (const float*)d_in[0];
  const int* ei = (const int*)d_in[1];
  const float* eattr = (const float*)d_in[2];
  const float* ctx = (const float*)d_in[3];
  const int* batch = (const int*)d_in[4];
  const int* role = (const int*)d_in[5];
  const int* side = (const int*)d_in[6];
  const int* form = (const int*)d_in[7];
  const int* alig = (const int*)d_in[8];
  const float* frame_t = (const float*)d_in[9];
  const float* emb_W = (const float*)d_in[10];
  const float* emb_b = (const float*)d_in[11];
  const float* role_tab = (const float*)d_in[12];
  const float* side_tab = (const float*)d_in[13];
  const float* ctx_W = (const float*)d_in[14];
  const float* ctx_b = (const float*)d_in[15];
  const float* form_tab = (const float*)d_in[16];
  const float* align_tab = (const float*)d_in[17];
  const float* temp_tab = (const float*)d_in[18];
  const float* gat_Wl = (const float*)d_in[19];
  const float* gat_bl = (const float*)d_in[20];
  const float* gat_Wr = (const float*)d_in[21];
  const float* gat_br = (const float*)d_in[22];
  const float* gat_We = (const float*)d_in[23];
  const float* gat_att = (const float*)d_in[24];
  const float* gat_bias = (const float*)d_in[25];
  const float* ln_g = (const float*)d_in[26];
  const float* ln_b = (const float*)d_in[27];
  const float* sp_W1 = (const float*)d_in[28];
  const float* sp_b1 = (const float*)d_in[29];
  const float* sp_W2 = (const float*)d_in[30];
  const float* sp_b2 = (const float*)d_in[31];
  const float* sp_Wg = (const float*)d_in[32];
  const float* sp_bg = (const float*)d_in[33];
  const float* fn_g = (const float*)d_in[34];
  const float* fn_b = (const float*)d_in[35];
  float* out = (float*)d_out;

  char* wp = (char*)d_ws;
  auto alloc = [&](size_t bytes) {
    void* p = (void*)wp;
    wp += (bytes + 255) & ~(size_t)255;
    return p;
  };
  float* c_ctx = (float*)alloc((size_t)Bb * HID * 4);
  float* h = (float*)alloc((size_t)N * HID * 4);
  float* xl = (float*)alloc((size_t)N * HH * 4);   // reused as gated[E][64] after GAT layers
  float* xr = (float*)alloc((size_t)N * HH * 4);
  float* la = (float*)alloc((size_t)N * EDIM * 4);
  float* u = (float*)alloc((size_t)N * HID * 4);
  float* v = (float*)alloc((size_t)N * HID * 4);
  int* deg_dst = (int*)alloc((size_t)N * 4);
  int* deg_src = (int*)alloc((size_t)N * 4);
  int* row_dst = (int*)alloc((size_t)N * 4);
  int* row_src = (int*)alloc((size_t)N * 4);
  int* cur_dst = (int*)alloc((size_t)N * 4);
  int* cur_src = (int*)alloc((size_t)N * 4);
  int* eid_dst = (int*)alloc((size_t)E * 4);
  int* eid_src = (int*)alloc((size_t)E * 4);
  int* esrc_dst = (int*)alloc((size_t)E * 4);
  float* gated = xl;  // [E][64] = 41 MB, spans xl+xr (both dead by then)

  hipMemsetAsync(deg_dst, 0, (size_t)N * 4, stream);
  hipMemsetAsync(deg_src, 0, (size_t)N * 4, stream);

  k_ctx<<<(Bb * HID + 255) / 256, 256, 0, stream>>>(ctx, ctx_W, ctx_b, form_tab, align_tab, form,
                                                    alig, c_ctx);
  k_node_init<<<(N * HID + 255) / 256, 256, 0, stream>>>(x, emb_W, emb_b, role, role_tab, side,
                                                         side_tab, frame_t, temp_tab, batch, c_ctx,
                                                         h);
  k_count<<<(E + 255) / 256, 256, 0, stream>>>(ei, deg_dst, deg_src);
  k_scan<<<1, 1024, 0, stream>>>(deg_dst, row_dst, cur_dst, N);
  k_scan<<<1, 1024, 0, stream>>>(deg_src, row_src, cur_src, N);
  k_scatter<<<(E + 255) / 256, 256, 0, stream>>>(ei, cur_dst, cur_src, eid_dst, eid_src, esrc_dst);
  k_loop_attr<<<(N + 255) / 256, 256, 0, stream>>>(row_dst, deg_dst, eid_dst, eattr, la);

  for (int i = 0; i < NL; ++i) {
    k_xlxr<<<(N + 15) / 16, 256, 0, stream>>>(h, gat_Wl + (size_t)i * HID * HH, gat_bl + i * HH,
                                              gat_Wr + (size_t)i * HID * HH, gat_br + i * HH, xl,
                                              xr);
    k_gat<<<N, 256, 0, stream>>>(xl, xr, eattr, la, row_dst, deg_dst, eid_dst, esrc_dst,
                                 gat_We + (size_t)i * EDIM * HH, gat_att + i * HH,
                                 gat_bias + i * HID, ln_g + i * HID, ln_b + i * HID, h);
  }

  k_uv<<<(N + 15) / 16, 256, 0, stream>>>(h, sp_W1, sp_b1, u, v);
  k_edge<<<(E + 255) / 256, 256, 0, stream>>>(u, v, ei, eid_src, sp_W2, sp_b2, sp_Wg, sp_bg,
                                              gated);
  k_pool<<<(N + 3) / 4, 256, 0, stream>>>(h, gated, row_src, deg_src, fn_g, fn_b, out);
}